// Round 1
// baseline (795.115 us; speedup 1.0000x reference)
//
#include <hip/hip_runtime.h>

#define TSTEPS 20
#define THRESV 1.0f
#define DECAYV 0.9375f

// ws layout (bytes):
//   [0      .. 32768)   float m1[8192]
//   [32768  .. 65536)   float m2[8192]
//   [65536  .. 65600)   float m3[16]
//   [65600  .. 73280)   u64 s_in_bits[20][48]
//   [73280  .. 93760)   u64 s1_bits[20][128]
//   [93760  .. 114240)  u64 s2_bits[20][128]

__global__ void snn_input_kernel(const float* __restrict__ image,
                                 unsigned long long* __restrict__ s_in_bits) {
    int i = blockIdx.x * 256 + threadIdx.x;   // 0..3071
    float img = image[i];
    float mi = 0.f;
    int word = i >> 6;
    int lane = i & 63;
    for (int t = 0; t < TSTEPS; ++t) {
        mi += img;
        bool fire = (mi >= THRESV);
        if (fire) mi -= THRESV;
        unsigned long long bm = __ballot(fire);
        if (lane == 0) s_in_bits[t * 48 + word] = bm;
    }
}

// wave 0 compacts a firing bitmask into an ascending index list in LDS.
// Deterministic (ascending order, no atomics).
__device__ __forceinline__ int compact_wave0(const unsigned long long* bits, int nwords,
                                             unsigned short* list, int* cntp) {
    int tid = threadIdx.x;
    if (tid < 64) {
        int cnt = 0;
        for (int w = 0; w < nwords; ++w) {
            unsigned long long word = bits ? bits[w] : 0ULL;
            if ((word >> tid) & 1ULL) {
                int pos = cnt + __popcll(word & ((1ULL << tid) - 1ULL));
                list[pos] = (unsigned short)((w << 6) + tid);
            }
            cnt += __popcll(word);
        }
        if (tid == 0) *cntp = cnt;
    }
    __syncthreads();
    return *cntp;
}

// One block handles 64 output columns of a hidden layer (N_out = 8192).
// 8 row-groups of 64 lanes each; group g sums list entries k = g, g+8, ...
// Fixed partition + fixed reduction tree => deterministic fp32 result.
template <int NWORDS>
__device__ __forceinline__ void layer_block(const float* __restrict__ W,
                                            const unsigned long long* __restrict__ in_bits,
                                            float* __restrict__ m,
                                            unsigned long long* __restrict__ out_bits,
                                            int blk, char* smem) {
    unsigned short* list = (unsigned short*)smem;            // 16 KiB
    float* partials = (float*)(smem + 16384);                // 2 KiB
    int* cntp = (int*)(smem + 16384 + 2048);
    int count = compact_wave0(in_bits, NWORDS, list, cntp);

    int tid = threadIdx.x;
    int col = tid & 63;
    int g = tid >> 6;                                        // 0..7
    const float* Wc = W + (size_t)blk * 64 + col;

    float acc = 0.f;
    int k = g;
    for (; k + 24 < count; k += 32) {                        // 4 loads in flight
        float a0 = Wc[(size_t)list[k]      * 8192];
        float a1 = Wc[(size_t)list[k + 8]  * 8192];
        float a2 = Wc[(size_t)list[k + 16] * 8192];
        float a3 = Wc[(size_t)list[k + 24] * 8192];
        acc += a0; acc += a1; acc += a2; acc += a3;
    }
    for (; k < count; k += 8)
        acc += Wc[(size_t)list[k] * 8192];

    partials[g * 64 + col] = acc;
    __syncthreads();

    if (g == 0) {  // wave 0: one lane per column
        float s = ((partials[col]       + partials[64 + col])
                 + (partials[128 + col] + partials[192 + col]))
                + ((partials[256 + col] + partials[320 + col])
                 + (partials[384 + col] + partials[448 + col]));
        int j = blk * 64 + col;
        float v = m[j] + s;
        bool fire = (v >= THRESV);
        if (fire) v -= THRESV;
        m[j] = fire ? v : v * DECAYV;
        unsigned long long bm = __ballot(fire);
        if (col == 0) out_bits[blk] = bm;
    }
}

// Layer 3: 10 outputs, W3 is 8192x10 (tiny). 32 groups x 16 cols.
__device__ __forceinline__ void layer3_block(const float* __restrict__ W3,
                                             const unsigned long long* __restrict__ s2p,
                                             float* __restrict__ m3,
                                             float* __restrict__ out_row, char* smem) {
    unsigned short* list = (unsigned short*)smem;
    float* partials = (float*)(smem + 16384);                // 32*16 floats
    int* cntp = (int*)(smem + 16384 + 2048);
    int count = compact_wave0(s2p, 128, list, cntp);

    int tid = threadIdx.x;
    int col = tid & 15;
    int g = tid >> 4;                                        // 0..31
    float acc = 0.f;
    if (col < 10) {
        for (int k = g; k < count; k += 32)
            acc += W3[(size_t)list[k] * 10 + col];
    }
    partials[g * 16 + col] = acc;
    __syncthreads();

    if (tid < 10) {
        float s = 0.f;
        for (int gg = 0; gg < 32; ++gg) s += partials[gg * 16 + tid];
        float v = m3[tid] + s;
        bool fire = (v >= THRESV);
        if (fire) v -= THRESV;
        m3[tid] = fire ? v : v * DECAYV;
        out_row[tid] = fire ? 1.f : 0.f;
    }
}

__global__ void __launch_bounds__(512)
snn_step_kernel(const float* __restrict__ W1, const float* __restrict__ W2,
                const float* __restrict__ W3,
                float* __restrict__ m1, float* __restrict__ m2, float* __restrict__ m3,
                const unsigned long long* __restrict__ sin_b,   // this step's input spikes
                const unsigned long long* __restrict__ s1p_b,   // prev-step layer1 spikes (or null)
                const unsigned long long* __restrict__ s2p_b,   // prev-step layer2 spikes (or null)
                unsigned long long* __restrict__ s1_out,
                unsigned long long* __restrict__ s2_out,
                float* __restrict__ out_row) {
    __shared__ __align__(16) char smem[16384 + 2048 + 16];
    int b = blockIdx.x;
    if (b < 128) {
        layer_block<48>(W1, sin_b, m1, s1_out, b, smem);
    } else if (b < 256) {
        layer_block<128>(W2, s1p_b, m2, s2_out, b - 128, smem);
    } else {
        layer3_block(W3, s2p_b, m3, out_row, smem);
    }
}

extern "C" void kernel_launch(void* const* d_in, const int* in_sizes, int n_in,
                              void* d_out, int out_size, void* d_ws, size_t ws_size,
                              hipStream_t stream) {
    const float* image = (const float*)d_in[0];
    const float* W1 = (const float*)d_in[1];
    const float* W2 = (const float*)d_in[2];
    const float* W3 = (const float*)d_in[3];
    float* out = (float*)d_out;

    char* ws = (char*)d_ws;
    float* m1 = (float*)ws;
    float* m2 = m1 + 8192;
    float* m3 = m2 + 8192;  // 16 floats
    unsigned long long* s_in_bits = (unsigned long long*)(ws + 65600);   // [20][48]
    unsigned long long* s1_bits = s_in_bits + TSTEPS * 48;               // [20][128]
    unsigned long long* s2_bits = s1_bits + TSTEPS * 128;                // [20][128]

    // zero membranes + output (harness poisons both; state must reset every launch)
    hipMemsetAsync(d_ws, 0, 65600, stream);
    hipMemsetAsync(d_out, 0, (size_t)out_size * sizeof(float), stream);

    snn_input_kernel<<<12, 256, 0, stream>>>(image, s_in_bits);

    for (int t = 0; t < TSTEPS; ++t) {
        snn_step_kernel<<<257, 512, 0, stream>>>(
            W1, W2, W3, m1, m2, m3,
            s_in_bits + t * 48,
            t ? s1_bits + (t - 1) * 128 : nullptr,
            t ? s2_bits + (t - 1) * 128 : nullptr,
            s1_bits + t * 128,
            s2_bits + t * 128,
            out + (t + 1) * 10);
    }
}

// Round 2
// 624.283 us; speedup vs baseline: 1.2736x; 1.2736x over previous
//
#include <hip/hip_runtime.h>

#define TSTEPS 20
#define THRESV 1.0f
#define DECAYV 0.9375f

// ws layout (bytes):
//   [0      .. 32768)   float m1[8192]
//   [32768  .. 65536)   float m2[8192]
//   [65536  .. 65600)   float m3[16]
//   [65600  .. 73280)   u64 s_in_bits[20][48]
//   [73280  .. 93760)   u64 s1_bits[20][128]
//   [93760  .. 114240)  u64 s2_bits[20][128]

__global__ void snn_input_kernel(const float* __restrict__ image,
                                 unsigned long long* __restrict__ s_in_bits) {
    int i = blockIdx.x * 256 + threadIdx.x;   // 0..3071
    float img = image[i];
    float mi = 0.f;
    int word = i >> 6;
    int lane = i & 63;
    for (int t = 0; t < TSTEPS; ++t) {
        mi += img;
        bool fire = (mi >= THRESV);
        if (fire) mi -= THRESV;
        unsigned long long bm = __ballot(fire);
        if (lane == 0) s_in_bits[t * 48 + word] = bm;
    }
}

// wave 0 compacts a firing bitmask into an ascending index list in LDS.
// Deterministic (ascending order, no atomics).
__device__ __forceinline__ int compact_wave0(const unsigned long long* bits, int nwords,
                                             unsigned short* list, int* cntp) {
    int tid = threadIdx.x;
    if (tid < 64) {
        int cnt = 0;
        for (int w = 0; w < nwords; ++w) {
            unsigned long long word = bits ? bits[w] : 0ULL;
            if ((word >> tid) & 1ULL) {
                int pos = cnt + __popcll(word & ((1ULL << tid) - 1ULL));
                list[pos] = (unsigned short)((w << 6) + tid);
            }
            cnt += __popcll(word);
        }
        if (tid == 0) *cntp = cnt;
    }
    __syncthreads();
    return *cntp;
}

// One block handles 64 output columns of a hidden layer (N_out = 8192).
// float4 gather: 16 lanes cover the 64 cols of one row; 32 row-groups,
// group g sums list entries k = g, g+32, ... (4-deep unrolled => 128 rows
// in flight per block). Fixed partition + fixed tree => deterministic.
template <int NWORDS>
__device__ __forceinline__ void layer_block(const float* __restrict__ W,
                                            const unsigned long long* __restrict__ in_bits,
                                            float* __restrict__ m,
                                            unsigned long long* __restrict__ out_bits,
                                            int blk, char* smem) {
    unsigned short* list = (unsigned short*)smem;            // 16 KiB
    float* partials = (float*)(smem + 16384);                // 8 KiB [32][64]
    int* cntp = (int*)(smem + 16384 + 8192);
    int count = compact_wave0(in_bits, NWORDS, list, cntp);

    int tid = threadIdx.x;
    int c4 = tid & 15;                                       // float4 column 0..15
    int g = tid >> 4;                                        // row-group 0..31
    const float4* Wc = (const float4*)(W + (size_t)blk * 64) + c4;  // row stride 2048 f4

    float ax = 0.f, ay = 0.f, az = 0.f, aw = 0.f;
    int k = g;
    for (; k + 96 < count; k += 128) {                       // 4 x 16B loads in flight
        float4 a0 = Wc[(size_t)list[k]      * 2048];
        float4 a1 = Wc[(size_t)list[k + 32] * 2048];
        float4 a2 = Wc[(size_t)list[k + 64] * 2048];
        float4 a3 = Wc[(size_t)list[k + 96] * 2048];
        ax += a0.x; ay += a0.y; az += a0.z; aw += a0.w;
        ax += a1.x; ay += a1.y; az += a1.z; aw += a1.w;
        ax += a2.x; ay += a2.y; az += a2.z; aw += a2.w;
        ax += a3.x; ay += a3.y; az += a3.z; aw += a3.w;
    }
    for (; k < count; k += 32) {
        float4 a = Wc[(size_t)list[k] * 2048];
        ax += a.x; ay += a.y; az += a.z; aw += a.w;
    }
    ((float4*)partials)[g * 16 + c4] = make_float4(ax, ay, az, aw);
    __syncthreads();

    if (tid < 64) {  // wave 0: one lane per column, fixed ascending order
        float s = 0.f;
        #pragma unroll
        for (int gg = 0; gg < 32; ++gg) s += partials[gg * 64 + tid];
        int j = blk * 64 + tid;
        float v = m[j] + s;
        bool fire = (v >= THRESV);
        if (fire) v -= THRESV;
        m[j] = fire ? v : v * DECAYV;
        unsigned long long bm = __ballot(fire);
        if (tid == 0) out_bits[blk] = bm;
    }
}

// Layer 3: 10 outputs, W3 is 8192x10 (tiny). 32 groups x 16 cols.
__device__ __forceinline__ void layer3_block(const float* __restrict__ W3,
                                             const unsigned long long* __restrict__ s2p,
                                             float* __restrict__ m3,
                                             float* __restrict__ out_row, char* smem) {
    unsigned short* list = (unsigned short*)smem;
    float* partials = (float*)(smem + 16384);                // 32*16 floats
    int* cntp = (int*)(smem + 16384 + 8192);
    int count = compact_wave0(s2p, 128, list, cntp);

    int tid = threadIdx.x;
    int col = tid & 15;
    int g = tid >> 4;                                        // 0..31
    float acc = 0.f;
    if (col < 10) {
        for (int k = g; k < count; k += 32)
            acc += W3[(size_t)list[k] * 10 + col];
    }
    partials[g * 16 + col] = acc;
    __syncthreads();

    if (tid < 10) {
        float s = 0.f;
        for (int gg = 0; gg < 32; ++gg) s += partials[gg * 16 + tid];
        float v = m3[tid] + s;
        bool fire = (v >= THRESV);
        if (fire) v -= THRESV;
        m3[tid] = fire ? v : v * DECAYV;
        out_row[tid] = fire ? 1.f : 0.f;
    }
}

__global__ void __launch_bounds__(512)
snn_step_kernel(const float* __restrict__ W1, const float* __restrict__ W2,
                const float* __restrict__ W3,
                float* __restrict__ m1, float* __restrict__ m2, float* __restrict__ m3,
                const unsigned long long* __restrict__ sin_b,   // this step's input spikes
                const unsigned long long* __restrict__ s1p_b,   // prev-step layer1 spikes (or null)
                const unsigned long long* __restrict__ s2p_b,   // prev-step layer2 spikes (or null)
                unsigned long long* __restrict__ s1_out,
                unsigned long long* __restrict__ s2_out,
                float* __restrict__ out_row) {
    __shared__ __align__(16) char smem[16384 + 8192 + 16];
    int b = blockIdx.x;
    if (b < 128) {
        layer_block<48>(W1, sin_b, m1, s1_out, b, smem);
    } else if (b < 256) {
        layer_block<128>(W2, s1p_b, m2, s2_out, b - 128, smem);
    } else {
        layer3_block(W3, s2p_b, m3, out_row, smem);
    }
}

extern "C" void kernel_launch(void* const* d_in, const int* in_sizes, int n_in,
                              void* d_out, int out_size, void* d_ws, size_t ws_size,
                              hipStream_t stream) {
    const float* image = (const float*)d_in[0];
    const float* W1 = (const float*)d_in[1];
    const float* W2 = (const float*)d_in[2];
    const float* W3 = (const float*)d_in[3];
    float* out = (float*)d_out;

    char* ws = (char*)d_ws;
    float* m1 = (float*)ws;
    float* m2 = m1 + 8192;
    float* m3 = m2 + 8192;  // 16 floats
    unsigned long long* s_in_bits = (unsigned long long*)(ws + 65600);   // [20][48]
    unsigned long long* s1_bits = s_in_bits + TSTEPS * 48;               // [20][128]
    unsigned long long* s2_bits = s1_bits + TSTEPS * 128;                // [20][128]

    // zero membranes + output (harness poisons both; state must reset every launch)
    hipMemsetAsync(d_ws, 0, 65600, stream);
    hipMemsetAsync(d_out, 0, (size_t)out_size * sizeof(float), stream);

    snn_input_kernel<<<12, 256, 0, stream>>>(image, s_in_bits);

    for (int t = 0; t < TSTEPS; ++t) {
        snn_step_kernel<<<257, 512, 0, stream>>>(
            W1, W2, W3, m1, m2, m3,
            s_in_bits + t * 48,
            t ? s1_bits + (t - 1) * 128 : nullptr,
            t ? s2_bits + (t - 1) * 128 : nullptr,
            s1_bits + t * 128,
            s2_bits + t * 128,
            out + (t + 1) * 10);
    }
}